// Round 1
// baseline (16752.747 us; speedup 1.0000x reference)
//
#include <hip/hip_runtime.h>

typedef unsigned short u16;
typedef unsigned int u32;
typedef short bf16x8 __attribute__((ext_vector_type(8)));
typedef float f32x4 __attribute__((ext_vector_type(4)));

#define B_  64
#define T_  512
#define H_  512
#define G_  2048

// LDS layout for lstm_rec: Ut[64][520] bf16 | hA[64][520] bf16 | zbuf[64][64] f32
#define REC_SMEM (66560 + 66560 + 16384)

__device__ __forceinline__ u16 f2bf(float f){
  u32 u = __float_as_uint(f);
  u32 r = u + 0x7FFFu + ((u >> 16) & 1u);   // RNE
  return (u16)(r >> 16);
}
__device__ __forceinline__ float bf2f(u16 v){
  return __uint_as_float(((u32)v) << 16);
}
__device__ __forceinline__ f32x4 mfma16(bf16x8 a, bf16x8 b, f32x4 c){
  return __builtin_amdgcn_mfma_f32_16x16x32_bf16(a, b, c, 0, 0, 0);
}
__device__ __forceinline__ float fsig(float x){ return 1.0f / (1.0f + __expf(-x)); }
__device__ __forceinline__ float ftanh(float x){ return 2.0f / (1.0f + __expf(-2.0f*x)) - 1.0f; }

// ---------------------------------------------------------------------------
// Transpose + cast: W [K][2048] f32 -> Wt [2048][K] bf16
// ---------------------------------------------------------------------------
__global__ __launch_bounds__(256) void transpose_cast(const float* __restrict__ in,
                                                      u16* __restrict__ out, int K){
  __shared__ float tile[32*33];
  const int k0 = blockIdx.y * 32, c0 = blockIdx.x * 32;
  const int tid = threadIdx.x;
  const int r = tid >> 3, cq = (tid & 7) * 4;
  float4 v = *(const float4*)(in + (size_t)(k0 + r) * 2048 + c0 + cq);
  tile[r*33 + cq + 0] = v.x;
  tile[r*33 + cq + 1] = v.y;
  tile[r*33 + cq + 2] = v.z;
  tile[r*33 + cq + 3] = v.w;
  __syncthreads();
  const int c = r, kq = cq;
  ushort4 ov;
  ov.x = f2bf(tile[(kq+0)*33 + c]);
  ov.y = f2bf(tile[(kq+1)*33 + c]);
  ov.z = f2bf(tile[(kq+2)*33 + c]);
  ov.w = f2bf(tile[(kq+3)*33 + c]);
  *(ushort4*)(out + (size_t)(c0 + c) * K + k0 + kq) = ov;
}

// ---------------------------------------------------------------------------
// GEMM: zx[dir][t][b][g] (bf16) = A[b*T+t][:] @ Wt[dir][g][:]^T + bias[dir][g]
// A is f32 (layer0: x) or bf16 (layer1: h0cat). 128x128 tile, BK=32, 4 waves.
// ---------------------------------------------------------------------------
template<typename AT>
__global__ __launch_bounds__(256) void gemm_zx(
    const AT* __restrict__ A, const u16* __restrict__ Btf, const u16* __restrict__ Btb,
    const float* __restrict__ biasf, const float* __restrict__ biasb,
    u16* __restrict__ zx, int K)
{
  __shared__ u16 As[128*40];
  __shared__ u16 Bs[128*40];
  const int dir = blockIdx.z;
  const u16* Bt = dir ? Btb : Btf;
  const float* bias = dir ? biasb : biasf;
  u16* out = zx + (size_t)dir * ((size_t)T_ * B_ * G_);
  const int m0 = blockIdx.y * 128, n0 = blockIdx.x * 128;
  const int tid = threadIdx.x;
  const int w = tid >> 6, l = tid & 63, i16 = l & 15, q = l >> 4;
  const int wm = w >> 1, wn = w & 1;
  const int sr = tid >> 1, sh = tid & 1;

  const f32x4 zf4 = {0.f, 0.f, 0.f, 0.f};
  f32x4 acc[4][4];
  #pragma unroll
  for (int a = 0; a < 4; a++)
    #pragma unroll
    for (int b = 0; b < 4; b++) acc[a][b] = zf4;

  for (int k0 = 0; k0 < K; k0 += 32){
    bf16x8 alo, ahi;
    if constexpr (sizeof(AT) == 4) {
      const float* src = (const float*)A + (size_t)(m0 + sr) * K + k0 + sh*16;
      float4 v0 = *(const float4*)(src);
      float4 v1 = *(const float4*)(src + 4);
      float4 v2 = *(const float4*)(src + 8);
      float4 v3 = *(const float4*)(src + 12);
      alo[0]=(short)f2bf(v0.x); alo[1]=(short)f2bf(v0.y); alo[2]=(short)f2bf(v0.z); alo[3]=(short)f2bf(v0.w);
      alo[4]=(short)f2bf(v1.x); alo[5]=(short)f2bf(v1.y); alo[6]=(short)f2bf(v1.z); alo[7]=(short)f2bf(v1.w);
      ahi[0]=(short)f2bf(v2.x); ahi[1]=(short)f2bf(v2.y); ahi[2]=(short)f2bf(v2.z); ahi[3]=(short)f2bf(v2.w);
      ahi[4]=(short)f2bf(v3.x); ahi[5]=(short)f2bf(v3.y); ahi[6]=(short)f2bf(v3.z); ahi[7]=(short)f2bf(v3.w);
    } else {
      const u16* src = (const u16*)A + (size_t)(m0 + sr) * K + k0 + sh*16;
      alo = *(const bf16x8*)(src);
      ahi = *(const bf16x8*)(src + 8);
    }
    const u16* bsrc = Bt + (size_t)(n0 + sr) * K + k0 + sh*16;
    bf16x8 blo = *(const bf16x8*)(bsrc);
    bf16x8 bhi = *(const bf16x8*)(bsrc + 8);
    *(bf16x8*)&As[sr*40 + sh*16 + 0] = alo;
    *(bf16x8*)&As[sr*40 + sh*16 + 8] = ahi;
    *(bf16x8*)&Bs[sr*40 + sh*16 + 0] = blo;
    *(bf16x8*)&Bs[sr*40 + sh*16 + 8] = bhi;
    __syncthreads();
    bf16x8 fa[4], fb[4];
    #pragma unroll
    for (int mt = 0; mt < 4; mt++) fa[mt] = *(const bf16x8*)&As[(wm*64 + mt*16 + i16)*40 + q*8];
    #pragma unroll
    for (int nt = 0; nt < 4; nt++) fb[nt] = *(const bf16x8*)&Bs[(wn*64 + nt*16 + i16)*40 + q*8];
    #pragma unroll
    for (int mt = 0; mt < 4; mt++)
      #pragma unroll
      for (int nt = 0; nt < 4; nt++)
        acc[mt][nt] = mfma16(fa[mt], fb[nt], acc[mt][nt]);
    __syncthreads();
  }
  // epilogue: C/D layout col=lane&15, row=(lane>>4)*4+reg
  #pragma unroll
  for (int nt = 0; nt < 4; nt++){
    const int col = n0 + wn*64 + nt*16 + i16;
    const float bv = bias[col];
    #pragma unroll
    for (int mt = 0; mt < 4; mt++){
      #pragma unroll
      for (int rr = 0; rr < 4; rr++){
        const int gr = m0 + wm*64 + mt*16 + q*4 + rr;   // = b*T + t
        const int bb = gr >> 9, tt = gr & 511;
        out[(size_t)(tt*64 + bb) * 2048 + col] = f2bf(acc[mt][nt][rr] + bv);
      }
    }
  }
}

// ---------------------------------------------------------------------------
// Persistent LSTM recurrence. Grid = 64 blocks: dir = bx>>5, slice = bx&31.
// Each WG owns 16 hidden units (64 gate cols), U-slice LDS/VGPR-resident.
// Per-step: MFMA z = h_{t-1} @ Uslice (+zx), elementwise, h exchange via
// global hbuf (parity double-buffered) + per-step device-scope counter barrier.
// ---------------------------------------------------------------------------
template<bool OUT_BF16>
__global__ __launch_bounds__(256, 1) void lstm_rec(
    const float* __restrict__ Uf, const float* __restrict__ Ub,
    const u16* __restrict__ zx, u16* __restrict__ hbuf,
    u32* __restrict__ cnt, u16* __restrict__ outb, float* __restrict__ outf)
{
  extern __shared__ char smem[];
  u16* Ut  = (u16*)smem;                    // [64][520] bf16, Ut[p][k] = U[k][col(p)]
  u16* hA  = (u16*)(smem + 66560);          // [64][520] bf16, h_{t-1}
  float* zbuf = (float*)(smem + 133120);    // [64][64]  f32 gate exchange

  const int dir = blockIdx.x >> 5;
  const int slice = blockIdx.x & 31;
  const int jbase = slice * 16;
  const int tid = threadIdx.x;
  const int w = tid >> 6, l = tid & 63, i16 = l & 15, q = l >> 4;
  const int wm = w >> 1, wn = w & 1;

  const float* U = dir ? Ub : Uf;
  u32* mycnt = cnt + dir * 512;
  const u16* zxd = zx + (size_t)dir * ((size_t)T_ * B_ * G_);

  // prologue: gather U columns {g*512 + jbase + c} -> transposed bf16 LDS
  {
    const int p = tid & 63, kq = tid >> 6;
    const int col = (p >> 4) * 512 + jbase + (p & 15);
    for (int k = kq; k < 512; k += 4)
      Ut[p*520 + k] = f2bf(U[(size_t)k * 2048 + col]);
  }
  __syncthreads();
  // hoist B fragments (static over time) into 128 VGPRs
  bf16x8 bfr[2][16];
  #pragma unroll
  for (int nt = 0; nt < 2; nt++)
    #pragma unroll
    for (int kk = 0; kk < 16; kk++)
      bfr[nt][kk] = *(const bf16x8*)&Ut[(wn*32 + nt*16 + i16)*520 + kk*32 + q*8];

  const int erow = tid >> 2;          // batch row 0..63
  const int ecg  = (tid & 3) * 4;     // 4 hidden cells per thread
  float cst[4] = {0.f, 0.f, 0.f, 0.f};
  const f32x4 zf4 = {0.f, 0.f, 0.f, 0.f};

  for (int t = 0; t < 512; t++){
    const int tz = dir ? (511 - t) : t;
    // prefetch zx gates (hidden under MFMA phase)
    ushort4 zu[4];
    {
      const u16* zr = zxd + (size_t)(tz*64 + erow) * 2048 + jbase + ecg;
      #pragma unroll
      for (int g2 = 0; g2 < 4; g2++) zu[g2] = *(const ushort4*)(zr + g2*512);
    }
    f32x4 acc[2][2];
    acc[0][0] = zf4; acc[0][1] = zf4; acc[1][0] = zf4; acc[1][1] = zf4;
    if (t > 0){
      // stage h_{t-1} (bf16 [64][512]) -> hA (padded)
      const u16* hp = hbuf + ((size_t)(((t-1)&1)*2 + dir) * 64 + erow) * 512 + (tid & 3) * 128;
      int4* ldst = (int4*)&hA[erow*520 + (tid & 3)*128];
      const int4* gsrc = (const int4*)hp;
      #pragma unroll
      for (int ii = 0; ii < 16; ii++) ldst[ii] = gsrc[ii];
      __syncthreads();
      #pragma unroll
      for (int kk = 0; kk < 16; kk++){
        bf16x8 a0 = *(const bf16x8*)&hA[(wm*32 +      i16)*520 + kk*32 + q*8];
        bf16x8 a1 = *(const bf16x8*)&hA[(wm*32 + 16 + i16)*520 + kk*32 + q*8];
        acc[0][0] = mfma16(a0, bfr[0][kk], acc[0][0]);
        acc[0][1] = mfma16(a0, bfr[1][kk], acc[0][1]);
        acc[1][0] = mfma16(a1, bfr[0][kk], acc[1][0]);
        acc[1][1] = mfma16(a1, bfr[1][kk], acc[1][1]);
      }
    }
    // scatter z to zbuf (C layout: row=(lane>>4)*4+reg, col=lane&15)
    #pragma unroll
    for (int mt = 0; mt < 2; mt++)
      #pragma unroll
      for (int nt = 0; nt < 2; nt++)
        #pragma unroll
        for (int rr = 0; rr < 4; rr++)
          zbuf[(wm*32 + mt*16 + q*4 + rr)*64 + wn*32 + nt*16 + i16] = acc[mt][nt][rr];
    __syncthreads();
    // elementwise LSTM cell (gate order i,f,g,o)
    float hvf[4];
    #pragma unroll
    for (int j = 0; j < 4; j++){
      const int ch = ecg + j;
      float z0 = zbuf[erow*64 +  0 + ch] + bf2f(((const u16*)&zu[0])[j]);
      float z1 = zbuf[erow*64 + 16 + ch] + bf2f(((const u16*)&zu[1])[j]);
      float z2 = zbuf[erow*64 + 32 + ch] + bf2f(((const u16*)&zu[2])[j]);
      float z3 = zbuf[erow*64 + 48 + ch] + bf2f(((const u16*)&zu[3])[j]);
      float ig = fsig(z0), fg = fsig(z1), gg = ftanh(z2), og = fsig(z3);
      cst[j] = fg * cst[j] + ig * gg;
      hvf[j] = og * ftanh(cst[j]);
    }
    ushort4 hv;
    hv.x = f2bf(hvf[0]); hv.y = f2bf(hvf[1]); hv.z = f2bf(hvf[2]); hv.w = f2bf(hvf[3]);
    *(ushort4*)(hbuf + ((size_t)((t&1)*2 + dir) * 64 + erow) * 512 + jbase + ecg) = hv;
    if (OUT_BF16){
      *(ushort4*)(outb + ((size_t)erow*512 + tz)*1024 + dir*512 + jbase + ecg) = hv;
    } else {
      float4 fv; fv.x = hvf[0]; fv.y = hvf[1]; fv.z = hvf[2]; fv.w = hvf[3];
      *(float4*)(outf + ((size_t)erow*512 + tz)*1024 + dir*512 + jbase + ecg) = fv;
    }
    if (t < 511){
      __syncthreads();
      __threadfence();
      if (tid == 0){
        __hip_atomic_fetch_add(&mycnt[t], 1u, __ATOMIC_RELEASE, __HIP_MEMORY_SCOPE_AGENT);
        while (__hip_atomic_load(&mycnt[t], __ATOMIC_ACQUIRE, __HIP_MEMORY_SCOPE_AGENT) < 32u)
          __builtin_amdgcn_s_sleep(2);
      }
      __threadfence();
      __syncthreads();
    }
  }
}

// ---------------------------------------------------------------------------
extern "C" void kernel_launch(void* const* d_in, const int* in_sizes, int n_in,
                              void* d_out, int out_size, void* d_ws, size_t ws_size,
                              hipStream_t stream) {
  const float* x   = (const float*)d_in[0];
  const float* W0f = (const float*)d_in[1];
  const float* U0f = (const float*)d_in[2];
  const float* b0f = (const float*)d_in[3];
  const float* W0b = (const float*)d_in[4];
  const float* U0b = (const float*)d_in[5];
  const float* b0b = (const float*)d_in[6];
  const float* W1f = (const float*)d_in[7];
  const float* U1f = (const float*)d_in[8];
  const float* b1f = (const float*)d_in[9];
  const float* W1b = (const float*)d_in[10];
  const float* U1b = (const float*)d_in[11];
  const float* b1b = (const float*)d_in[12];

  char* ws = (char*)d_ws;
  size_t off = 0;
  u16* Wt0f = (u16*)(ws + off); off += (size_t)2048*512*2;
  u16* Wt0b = (u16*)(ws + off); off += (size_t)2048*512*2;
  u16* Wt1f = (u16*)(ws + off); off += (size_t)2048*1024*2;
  u16* Wt1b = (u16*)(ws + off); off += (size_t)2048*1024*2;
  u16* zx   = (u16*)(ws + off); off += (size_t)2*512*64*2048*2;
  u16* h0   = (u16*)(ws + off); off += (size_t)64*512*1024*2;
  u16* hbuf = (u16*)(ws + off); off += (size_t)2*2*64*512*2;
  u32* cnt  = (u32*)(ws + off); off += (size_t)2*2*512*4;
  (void)ws_size; (void)in_sizes; (void)n_in; (void)out_size;

  hipMemsetAsync(cnt, 0, 2*2*512*4, stream);
  hipFuncSetAttribute(reinterpret_cast<const void*>(&lstm_rec<true>),
                      hipFuncAttributeMaxDynamicSharedMemorySize, REC_SMEM);
  hipFuncSetAttribute(reinterpret_cast<const void*>(&lstm_rec<false>),
                      hipFuncAttributeMaxDynamicSharedMemorySize, REC_SMEM);

  transpose_cast<<<dim3(64, 16), 256, 0, stream>>>(W0f, Wt0f, 512);
  transpose_cast<<<dim3(64, 16), 256, 0, stream>>>(W0b, Wt0b, 512);
  transpose_cast<<<dim3(64, 32), 256, 0, stream>>>(W1f, Wt1f, 1024);
  transpose_cast<<<dim3(64, 32), 256, 0, stream>>>(W1b, Wt1b, 1024);

  gemm_zx<float><<<dim3(16, 256, 2), 256, 0, stream>>>(x, Wt0f, Wt0b, b0f, b0b, zx, 512);
  lstm_rec<true><<<64, 256, REC_SMEM, stream>>>(U0f, U0b, zx, hbuf, cnt, h0, nullptr);
  gemm_zx<u16><<<dim3(16, 256, 2), 256, 0, stream>>>(h0, Wt1f, Wt1b, b1f, b1b, zx, 1024);
  lstm_rec<false><<<64, 256, REC_SMEM, stream>>>(U1f, U1b, zx, hbuf, cnt + 1024, nullptr,
                                                 (float*)d_out);
}

// Round 2
// 9905.188 us; speedup vs baseline: 1.6913x; 1.6913x over previous
//
#include <hip/hip_runtime.h>

typedef unsigned short u16;
typedef unsigned int u32;
typedef short bf16x8 __attribute__((ext_vector_type(8)));
typedef float f32x4 __attribute__((ext_vector_type(4)));
typedef int i32x4 __attribute__((ext_vector_type(4)));

#define B_  64
#define T_  512
#define H_  512
#define G_  2048

// lstm_rec LDS: prologue Ut[128][520] bf16 (133120 B);
// loop overlays: hA[64][520] bf16 (66560 B) | zbuf[64][132] f32 (33792 B)
#define REC_SMEM 133120

__device__ __forceinline__ u16 f2bf(float f){
  u32 u = __float_as_uint(f);
  u32 r = u + 0x7FFFu + ((u >> 16) & 1u);   // RNE
  return (u16)(r >> 16);
}
__device__ __forceinline__ float bf2f(u16 v){
  return __uint_as_float(((u32)v) << 16);
}
__device__ __forceinline__ f32x4 mfma16(bf16x8 a, bf16x8 b, f32x4 c){
  return __builtin_amdgcn_mfma_f32_16x16x32_bf16(a, b, c, 0, 0, 0);
}
__device__ __forceinline__ float fsig(float x){ return 1.0f / (1.0f + __expf(-x)); }
__device__ __forceinline__ float ftanh(float x){ return 2.0f / (1.0f + __expf(-2.0f*x)) - 1.0f; }

// ---------------------------------------------------------------------------
// Transpose + cast: W [K][2048] f32 -> Wt [2048][K] bf16
// ---------------------------------------------------------------------------
__global__ __launch_bounds__(256) void transpose_cast(const float* __restrict__ in,
                                                      u16* __restrict__ out, int K){
  __shared__ float tile[32*33];
  const int k0 = blockIdx.y * 32, c0 = blockIdx.x * 32;
  const int tid = threadIdx.x;
  const int r = tid >> 3, cq = (tid & 7) * 4;
  float4 v = *(const float4*)(in + (size_t)(k0 + r) * 2048 + c0 + cq);
  tile[r*33 + cq + 0] = v.x;
  tile[r*33 + cq + 1] = v.y;
  tile[r*33 + cq + 2] = v.z;
  tile[r*33 + cq + 3] = v.w;
  __syncthreads();
  const int c = r, kq = cq;
  ushort4 ov;
  ov.x = f2bf(tile[(kq+0)*33 + c]);
  ov.y = f2bf(tile[(kq+1)*33 + c]);
  ov.z = f2bf(tile[(kq+2)*33 + c]);
  ov.w = f2bf(tile[(kq+3)*33 + c]);
  *(ushort4*)(out + (size_t)(c0 + c) * K + k0 + kq) = ov;
}

// ---------------------------------------------------------------------------
// GEMM: zx[dir][t][b][g] (bf16) = A[b*T+t][:] @ Wt[dir][g][:]^T + bias[dir][g]
// ---------------------------------------------------------------------------
template<typename AT>
__global__ __launch_bounds__(256) void gemm_zx(
    const AT* __restrict__ A, const u16* __restrict__ Btf, const u16* __restrict__ Btb,
    const float* __restrict__ biasf, const float* __restrict__ biasb,
    u16* __restrict__ zx, int K)
{
  __shared__ u16 As[128*40];
  __shared__ u16 Bs[128*40];
  const int dir = blockIdx.z;
  const u16* Bt = dir ? Btb : Btf;
  const float* bias = dir ? biasb : biasf;
  u16* out = zx + (size_t)dir * ((size_t)T_ * B_ * G_);
  const int m0 = blockIdx.y * 128, n0 = blockIdx.x * 128;
  const int tid = threadIdx.x;
  const int w = tid >> 6, l = tid & 63, i16 = l & 15, q = l >> 4;
  const int wm = w >> 1, wn = w & 1;
  const int sr = tid >> 1, sh = tid & 1;

  const f32x4 zf4 = {0.f, 0.f, 0.f, 0.f};
  f32x4 acc[4][4];
  #pragma unroll
  for (int a = 0; a < 4; a++)
    #pragma unroll
    for (int b = 0; b < 4; b++) acc[a][b] = zf4;

  for (int k0 = 0; k0 < K; k0 += 32){
    bf16x8 alo, ahi;
    if constexpr (sizeof(AT) == 4) {
      const float* src = (const float*)A + (size_t)(m0 + sr) * K + k0 + sh*16;
      float4 v0 = *(const float4*)(src);
      float4 v1 = *(const float4*)(src + 4);
      float4 v2 = *(const float4*)(src + 8);
      float4 v3 = *(const float4*)(src + 12);
      alo[0]=(short)f2bf(v0.x); alo[1]=(short)f2bf(v0.y); alo[2]=(short)f2bf(v0.z); alo[3]=(short)f2bf(v0.w);
      alo[4]=(short)f2bf(v1.x); alo[5]=(short)f2bf(v1.y); alo[6]=(short)f2bf(v1.z); alo[7]=(short)f2bf(v1.w);
      ahi[0]=(short)f2bf(v2.x); ahi[1]=(short)f2bf(v2.y); ahi[2]=(short)f2bf(v2.z); ahi[3]=(short)f2bf(v2.w);
      ahi[4]=(short)f2bf(v3.x); ahi[5]=(short)f2bf(v3.y); ahi[6]=(short)f2bf(v3.z); ahi[7]=(short)f2bf(v3.w);
    } else {
      const u16* src = (const u16*)A + (size_t)(m0 + sr) * K + k0 + sh*16;
      alo = *(const bf16x8*)(src);
      ahi = *(const bf16x8*)(src + 8);
    }
    const u16* bsrc = Bt + (size_t)(n0 + sr) * K + k0 + sh*16;
    bf16x8 blo = *(const bf16x8*)(bsrc);
    bf16x8 bhi = *(const bf16x8*)(bsrc + 8);
    *(bf16x8*)&As[sr*40 + sh*16 + 0] = alo;
    *(bf16x8*)&As[sr*40 + sh*16 + 8] = ahi;
    *(bf16x8*)&Bs[sr*40 + sh*16 + 0] = blo;
    *(bf16x8*)&Bs[sr*40 + sh*16 + 8] = bhi;
    __syncthreads();
    bf16x8 fa[4], fb[4];
    #pragma unroll
    for (int mt = 0; mt < 4; mt++) fa[mt] = *(const bf16x8*)&As[(wm*64 + mt*16 + i16)*40 + q*8];
    #pragma unroll
    for (int nt = 0; nt < 4; nt++) fb[nt] = *(const bf16x8*)&Bs[(wn*64 + nt*16 + i16)*40 + q*8];
    #pragma unroll
    for (int mt = 0; mt < 4; mt++)
      #pragma unroll
      for (int nt = 0; nt < 4; nt++)
        acc[mt][nt] = mfma16(fa[mt], fb[nt], acc[mt][nt]);
    __syncthreads();
  }
  #pragma unroll
  for (int nt = 0; nt < 4; nt++){
    const int col = n0 + wn*64 + nt*16 + i16;
    const float bv = bias[col];
    #pragma unroll
    for (int mt = 0; mt < 4; mt++){
      #pragma unroll
      for (int rr = 0; rr < 4; rr++){
        const int gr = m0 + wm*64 + mt*16 + q*4 + rr;   // = b*T + t
        const int bb = gr >> 9, tt = gr & 511;
        out[(size_t)(tt*64 + bb) * 2048 + col] = f2bf(acc[mt][nt][rr] + bv);
      }
    }
  }
}

// ---------------------------------------------------------------------------
// Persistent LSTM recurrence, fence-free cross-WG exchange.
// Grid = 32 blocks: dir = bx>>4, slice = bx&15; each WG owns 32 hidden units
// (128 gate cols). U fragments VGPR-resident (128 VGPRs/wave). Per step:
// h_{t-1} read via sc0+sc1 loads (MALL, bypass stale L1/L2), MFMA z = h@U,
// elementwise cell, h_t written via sc0+sc1 stores, release = s_waitcnt
// vmcnt(0) + relaxed agent atomic counter; NO cache-maintenance fences, so
// the zx stream stays L2-warm.
// ---------------------------------------------------------------------------
template<bool OUT_BF16>
__global__ __launch_bounds__(256, 1) void lstm_rec(
    const float* __restrict__ Uf, const float* __restrict__ Ub,
    const u16* __restrict__ zx, u16* __restrict__ hbuf,
    u32* __restrict__ cnt, u16* __restrict__ outb, float* __restrict__ outf)
{
  extern __shared__ char smem[];
  u16* Ut = (u16*)smem;                   // prologue only
  u16* hA = (u16*)smem;                   // loop: [64][520]
  float* zbuf = (float*)(smem + 66560);   // loop: [64][132]

  const int dir = blockIdx.x >> 4;
  const int slice = blockIdx.x & 15;
  const int jbase = slice * 32;
  const int tid = threadIdx.x;
  const int w = tid >> 6, l = tid & 63, i16 = l & 15, q = l >> 4;

  const float* U = dir ? Ub : Uf;
  u32* mycnt = cnt + dir * 512;
  const u16* zxd = zx + (size_t)dir * ((size_t)T_ * B_ * G_);

  // prologue: stage U-slice transposed to LDS (coalesced f32 reads)
  {
    const int p = tid & 127, kq = tid >> 7;
    const int gcol = (p >> 5) * 512 + jbase + (p & 31);
    for (int k = kq; k < 512; k += 2)
      Ut[p*520 + k] = f2bf(U[(size_t)k * 2048 + gcol]);
  }
  __syncthreads();
  // hoist B fragments (static over time): wave w covers cols [w*32, w*32+32)
  bf16x8 bfr[2][16];
  #pragma unroll
  for (int nt = 0; nt < 2; nt++)
    #pragma unroll
    for (int kk = 0; kk < 16; kk++)
      bfr[nt][kk] = *(const bf16x8*)&Ut[(w*32 + nt*16 + i16)*520 + kk*32 + q*8];
  __syncthreads();

  const int erow = tid >> 2;          // batch row 0..63
  const int ecg  = (tid & 3) * 8;     // 8 hidden cells per thread
  float cst[8];
  #pragma unroll
  for (int j = 0; j < 8; j++) cst[j] = 0.f;
  const f32x4 zf4 = {0.f, 0.f, 0.f, 0.f};

  for (int t = 0; t < 512; t++){
    const int tz = dir ? (511 - t) : t;
    // zx gates for this step (normal cached loads; L2 stays warm)
    i32x4 zu[4];
    {
      const u16* zr = zxd + (size_t)(tz*64 + erow) * 2048 + jbase + ecg;
      #pragma unroll
      for (int g = 0; g < 4; g++) zu[g] = *(const i32x4*)(zr + g*512);
    }
    f32x4 acc[4][2];
    #pragma unroll
    for (int mt = 0; mt < 4; mt++){ acc[mt][0] = zf4; acc[mt][1] = zf4; }

    if (t > 0){
      // read full h_{t-1} (64 KB) straight from the coherence point
      const i32x4* hp = (const i32x4*)(hbuf + ((size_t)(((t-1)&1)*2 + dir)) * 32768) + tid*16;
      i32x4 hv16[16];
      #pragma unroll
      for (int ii = 0; ii < 16; ii++)
        asm volatile("global_load_dwordx4 %0, %1, off sc0 sc1"
                     : "=v"(hv16[ii]) : "v"(hp + ii));
      asm volatile("s_waitcnt vmcnt(0)" ::: "memory");
      i32x4* ldst = (i32x4*)&hA[(tid>>2)*520 + (tid&3)*128];
      #pragma unroll
      for (int ii = 0; ii < 16; ii++) ldst[ii] = hv16[ii];
      __syncthreads();
      #pragma unroll
      for (int kk = 0; kk < 16; kk++){
        bf16x8 a[4];
        #pragma unroll
        for (int mt = 0; mt < 4; mt++)
          a[mt] = *(const bf16x8*)&hA[(mt*16 + i16)*520 + kk*32 + q*8];
        #pragma unroll
        for (int mt = 0; mt < 4; mt++){
          acc[mt][0] = mfma16(a[mt], bfr[0][kk], acc[mt][0]);
          acc[mt][1] = mfma16(a[mt], bfr[1][kk], acc[mt][1]);
        }
      }
    }
    // scatter z to zbuf (C layout row=(lane>>4)*4+reg, col=lane&15)
    #pragma unroll
    for (int mt = 0; mt < 4; mt++)
      #pragma unroll
      for (int nt = 0; nt < 2; nt++)
        #pragma unroll
        for (int rr = 0; rr < 4; rr++)
          zbuf[(mt*16 + q*4 + rr)*132 + w*32 + nt*16 + i16] = acc[mt][nt][rr];
    __syncthreads();
    // elementwise LSTM cell (gate order i,f,g,o)
    float hvf[8];
    i32x4 hpk;
    u16* hpku = (u16*)&hpk;
    #pragma unroll
    for (int j = 0; j < 8; j++){
      const int ch = ecg + j;
      const float* zb = &zbuf[erow*132 + ch];
      float z0 = zb[ 0] + bf2f(((const u16*)&zu[0])[j]);
      float z1 = zb[32] + bf2f(((const u16*)&zu[1])[j]);
      float z2 = zb[64] + bf2f(((const u16*)&zu[2])[j]);
      float z3 = zb[96] + bf2f(((const u16*)&zu[3])[j]);
      float ig = fsig(z0), fg = fsig(z1), gg = ftanh(z2), og = fsig(z3);
      cst[j] = fg * cst[j] + ig * gg;
      hvf[j] = og * ftanh(cst[j]);
      hpku[j] = f2bf(hvf[j]);
    }
    // write h_t slice through to the coherence point
    u16* hwp = hbuf + ((size_t)((t&1)*2 + dir)) * 32768 + erow*512 + jbase + ecg;
    asm volatile("global_store_dwordx4 %0, %1, off sc0 sc1" :: "v"(hwp), "v"(hpk) : "memory");
    if (OUT_BF16){
      *(i32x4*)(outb + ((size_t)erow*512 + tz)*1024 + dir*512 + jbase + ecg) = hpk;
    } else {
      float* op = outf + ((size_t)erow*512 + tz)*1024 + dir*512 + jbase + ecg;
      float4 f0 = {hvf[0], hvf[1], hvf[2], hvf[3]};
      float4 f1 = {hvf[4], hvf[5], hvf[6], hvf[7]};
      *(float4*)(op) = f0;
      *(float4*)(op + 4) = f1;
    }
    if (t < 511){
      // release: h-store acked at MALL, then relaxed agent counter. No fences.
      asm volatile("s_waitcnt vmcnt(0)" ::: "memory");
      __syncthreads();
      if (tid == 0){
        __hip_atomic_fetch_add(&mycnt[t], 1u, __ATOMIC_RELAXED, __HIP_MEMORY_SCOPE_AGENT);
        while (__hip_atomic_load(&mycnt[t], __ATOMIC_RELAXED, __HIP_MEMORY_SCOPE_AGENT) < 16u)
          __builtin_amdgcn_s_sleep(1);
      }
      __syncthreads();
    }
  }
}

// ---------------------------------------------------------------------------
extern "C" void kernel_launch(void* const* d_in, const int* in_sizes, int n_in,
                              void* d_out, int out_size, void* d_ws, size_t ws_size,
                              hipStream_t stream) {
  const float* x   = (const float*)d_in[0];
  const float* W0f = (const float*)d_in[1];
  const float* U0f = (const float*)d_in[2];
  const float* b0f = (const float*)d_in[3];
  const float* W0b = (const float*)d_in[4];
  const float* U0b = (const float*)d_in[5];
  const float* b0b = (const float*)d_in[6];
  const float* W1f = (const float*)d_in[7];
  const float* U1f = (const float*)d_in[8];
  const float* b1f = (const float*)d_in[9];
  const float* W1b = (const float*)d_in[10];
  const float* U1b = (const float*)d_in[11];
  const float* b1b = (const float*)d_in[12];

  char* ws = (char*)d_ws;
  size_t off = 0;
  u16* Wt0f = (u16*)(ws + off); off += (size_t)2048*512*2;
  u16* Wt0b = (u16*)(ws + off); off += (size_t)2048*512*2;
  u16* Wt1f = (u16*)(ws + off); off += (size_t)2048*1024*2;
  u16* Wt1b = (u16*)(ws + off); off += (size_t)2048*1024*2;
  u16* zx   = (u16*)(ws + off); off += (size_t)2*512*64*2048*2;
  u16* h0   = (u16*)(ws + off); off += (size_t)64*512*1024*2;
  u16* hbuf = (u16*)(ws + off); off += (size_t)2*2*64*512*2;
  u32* cnt  = (u32*)(ws + off); off += (size_t)2*2*512*4;
  (void)ws_size; (void)in_sizes; (void)n_in; (void)out_size;

  hipMemsetAsync(cnt, 0, 2*2*512*4, stream);
  hipFuncSetAttribute(reinterpret_cast<const void*>(&lstm_rec<true>),
                      hipFuncAttributeMaxDynamicSharedMemorySize, REC_SMEM);
  hipFuncSetAttribute(reinterpret_cast<const void*>(&lstm_rec<false>),
                      hipFuncAttributeMaxDynamicSharedMemorySize, REC_SMEM);

  transpose_cast<<<dim3(64, 16), 256, 0, stream>>>(W0f, Wt0f, 512);
  transpose_cast<<<dim3(64, 16), 256, 0, stream>>>(W0b, Wt0b, 512);
  transpose_cast<<<dim3(64, 32), 256, 0, stream>>>(W1f, Wt1f, 1024);
  transpose_cast<<<dim3(64, 32), 256, 0, stream>>>(W1b, Wt1b, 1024);

  gemm_zx<float><<<dim3(16, 256, 2), 256, 0, stream>>>(x, Wt0f, Wt0b, b0f, b0b, zx, 512);
  lstm_rec<true><<<32, 256, REC_SMEM, stream>>>(U0f, U0b, zx, hbuf, cnt, h0, nullptr);
  gemm_zx<u16><<<dim3(16, 256, 2), 256, 0, stream>>>(h0, Wt1f, Wt1b, b1f, b1b, zx, 1024);
  lstm_rec<false><<<32, 256, REC_SMEM, stream>>>(U1f, U1b, zx, hbuf, cnt + 1024, nullptr,
                                                 (float*)d_out);
}

// Round 3
// 9253.265 us; speedup vs baseline: 1.8105x; 1.0705x over previous
//
#include <hip/hip_runtime.h>

typedef unsigned short u16;
typedef unsigned int u32;
typedef short bf16x8 __attribute__((ext_vector_type(8)));
typedef float f32x4 __attribute__((ext_vector_type(4)));
typedef int i32x4 __attribute__((ext_vector_type(4)));

#define B_  64
#define T_  512
#define H_  512
#define G_  2048

// lstm_rec LDS: prologue Ut[128][520] bf16 (133120 B);
// loop overlays: hA[64][520] bf16 (66560 B) | zbuf[64][132] f32 (33792 B)
#define REC_SMEM 133120

__device__ __forceinline__ u16 f2bf(float f){
  u32 u = __float_as_uint(f);
  u32 r = u + 0x7FFFu + ((u >> 16) & 1u);   // RNE
  return (u16)(r >> 16);
}
__device__ __forceinline__ float bf2f(u16 v){
  return __uint_as_float(((u32)v) << 16);
}
__device__ __forceinline__ f32x4 mfma16(bf16x8 a, bf16x8 b, f32x4 c){
  return __builtin_amdgcn_mfma_f32_16x16x32_bf16(a, b, c, 0, 0, 0);
}
__device__ __forceinline__ float fsig(float x){ return 1.0f / (1.0f + __expf(-x)); }
__device__ __forceinline__ float ftanh(float x){ return 2.0f / (1.0f + __expf(-2.0f*x)) - 1.0f; }

// ---------------------------------------------------------------------------
// Transpose + cast: W [K][2048] f32 -> Wt [2048][K] bf16
// ---------------------------------------------------------------------------
__global__ __launch_bounds__(256) void transpose_cast(const float* __restrict__ in,
                                                      u16* __restrict__ out, int K){
  __shared__ float tile[32*33];
  const int k0 = blockIdx.y * 32, c0 = blockIdx.x * 32;
  const int tid = threadIdx.x;
  const int r = tid >> 3, cq = (tid & 7) * 4;
  float4 v = *(const float4*)(in + (size_t)(k0 + r) * 2048 + c0 + cq);
  tile[r*33 + cq + 0] = v.x;
  tile[r*33 + cq + 1] = v.y;
  tile[r*33 + cq + 2] = v.z;
  tile[r*33 + cq + 3] = v.w;
  __syncthreads();
  const int c = r, kq = cq;
  ushort4 ov;
  ov.x = f2bf(tile[(kq+0)*33 + c]);
  ov.y = f2bf(tile[(kq+1)*33 + c]);
  ov.z = f2bf(tile[(kq+2)*33 + c]);
  ov.w = f2bf(tile[(kq+3)*33 + c]);
  *(ushort4*)(out + (size_t)(c0 + c) * K + k0 + kq) = ov;
}

// ---------------------------------------------------------------------------
// GEMM: zx[dir][t][b][g] (bf16) = A[b*T+t][:] @ Wt[dir][g][:]^T + bias[dir][g]
// ---------------------------------------------------------------------------
template<typename AT>
__global__ __launch_bounds__(256) void gemm_zx(
    const AT* __restrict__ A, const u16* __restrict__ Btf, const u16* __restrict__ Btb,
    const float* __restrict__ biasf, const float* __restrict__ biasb,
    u16* __restrict__ zx, int K)
{
  __shared__ u16 As[128*40];
  __shared__ u16 Bs[128*40];
  const int dir = blockIdx.z;
  const u16* Bt = dir ? Btb : Btf;
  const float* bias = dir ? biasb : biasf;
  u16* out = zx + (size_t)dir * ((size_t)T_ * B_ * G_);
  const int m0 = blockIdx.y * 128, n0 = blockIdx.x * 128;
  const int tid = threadIdx.x;
  const int w = tid >> 6, l = tid & 63, i16 = l & 15, q = l >> 4;
  const int wm = w >> 1, wn = w & 1;
  const int sr = tid >> 1, sh = tid & 1;

  const f32x4 zf4 = {0.f, 0.f, 0.f, 0.f};
  f32x4 acc[4][4];
  #pragma unroll
  for (int a = 0; a < 4; a++)
    #pragma unroll
    for (int b = 0; b < 4; b++) acc[a][b] = zf4;

  for (int k0 = 0; k0 < K; k0 += 32){
    bf16x8 alo, ahi;
    if constexpr (sizeof(AT) == 4) {
      const float* src = (const float*)A + (size_t)(m0 + sr) * K + k0 + sh*16;
      float4 v0 = *(const float4*)(src);
      float4 v1 = *(const float4*)(src + 4);
      float4 v2 = *(const float4*)(src + 8);
      float4 v3 = *(const float4*)(src + 12);
      alo[0]=(short)f2bf(v0.x); alo[1]=(short)f2bf(v0.y); alo[2]=(short)f2bf(v0.z); alo[3]=(short)f2bf(v0.w);
      alo[4]=(short)f2bf(v1.x); alo[5]=(short)f2bf(v1.y); alo[6]=(short)f2bf(v1.z); alo[7]=(short)f2bf(v1.w);
      ahi[0]=(short)f2bf(v2.x); ahi[1]=(short)f2bf(v2.y); ahi[2]=(short)f2bf(v2.z); ahi[3]=(short)f2bf(v2.w);
      ahi[4]=(short)f2bf(v3.x); ahi[5]=(short)f2bf(v3.y); ahi[6]=(short)f2bf(v3.z); ahi[7]=(short)f2bf(v3.w);
    } else {
      const u16* src = (const u16*)A + (size_t)(m0 + sr) * K + k0 + sh*16;
      alo = *(const bf16x8*)(src);
      ahi = *(const bf16x8*)(src + 8);
    }
    const u16* bsrc = Bt + (size_t)(n0 + sr) * K + k0 + sh*16;
    bf16x8 blo = *(const bf16x8*)(bsrc);
    bf16x8 bhi = *(const bf16x8*)(bsrc + 8);
    *(bf16x8*)&As[sr*40 + sh*16 + 0] = alo;
    *(bf16x8*)&As[sr*40 + sh*16 + 8] = ahi;
    *(bf16x8*)&Bs[sr*40 + sh*16 + 0] = blo;
    *(bf16x8*)&Bs[sr*40 + sh*16 + 8] = bhi;
    __syncthreads();
    bf16x8 fa[4], fb[4];
    #pragma unroll
    for (int mt = 0; mt < 4; mt++) fa[mt] = *(const bf16x8*)&As[(wm*64 + mt*16 + i16)*40 + q*8];
    #pragma unroll
    for (int nt = 0; nt < 4; nt++) fb[nt] = *(const bf16x8*)&Bs[(wn*64 + nt*16 + i16)*40 + q*8];
    #pragma unroll
    for (int mt = 0; mt < 4; mt++)
      #pragma unroll
      for (int nt = 0; nt < 4; nt++)
        acc[mt][nt] = mfma16(fa[mt], fb[nt], acc[mt][nt]);
    __syncthreads();
  }
  #pragma unroll
  for (int nt = 0; nt < 4; nt++){
    const int col = n0 + wn*64 + nt*16 + i16;
    const float bv = bias[col];
    #pragma unroll
    for (int mt = 0; mt < 4; mt++){
      #pragma unroll
      for (int rr = 0; rr < 4; rr++){
        const int gr = m0 + wm*64 + mt*16 + q*4 + rr;   // = b*T + t
        const int bb = gr >> 9, tt = gr & 511;
        out[(size_t)(tt*64 + bb) * 2048 + col] = f2bf(acc[mt][nt][rr] + bv);
      }
    }
  }
}

// ---------------------------------------------------------------------------
// Persistent LSTM recurrence, fence-free, RMW-free cross-WG sync.
// Grid = 32 blocks: dir = bx>>4, slice = bx&15; each WG owns 32 hidden units
// (128 gate cols). Sync protocol per step t:
//   producer: h-store (sc0 sc1) -> vmcnt(0) -> issue out-store -> barrier ->
//             tid0 stores flags[t][wg]=t+1 (plain sc0 sc1 store, write-once slot)
//   consumer: wave0 lanes0-15 poll flags[t-1][0..15] (one coalesced 64B line
//             per iteration) -> __syncthreads -> h loads (sc0 sc1).
// No atomics, no cache-maintenance fences; zx stream stays L2-warm.
// ---------------------------------------------------------------------------
template<bool OUT_BF16>
__global__ __launch_bounds__(256, 1) void lstm_rec(
    const float* __restrict__ Uf, const float* __restrict__ Ub,
    const u16* __restrict__ zx, u16* __restrict__ hbuf,
    u32* __restrict__ flags, u16* __restrict__ outb, float* __restrict__ outf)
{
  extern __shared__ char smem[];
  u16* Ut = (u16*)smem;                   // prologue only
  u16* hA = (u16*)smem;                   // loop: [64][520]
  float* zbuf = (float*)(smem + 66560);   // loop: [64][132]

  const int dir = blockIdx.x >> 4;
  const int slice = blockIdx.x & 15;
  const int jbase = slice * 32;
  const int tid = threadIdx.x;
  const int w = tid >> 6, l = tid & 63, i16 = l & 15, q = l >> 4;

  const float* U = dir ? Ub : Uf;
  u32* myflags = flags + (size_t)dir * (512 * 16);
  const u16* zxd = zx + (size_t)dir * ((size_t)T_ * B_ * G_);

  // prologue: stage U-slice transposed to LDS (coalesced f32 reads)
  {
    const int p = tid & 127, kq = tid >> 7;
    const int gcol = (p >> 5) * 512 + jbase + (p & 31);
    for (int k = kq; k < 512; k += 2)
      Ut[p*520 + k] = f2bf(U[(size_t)k * 2048 + gcol]);
  }
  __syncthreads();
  // hoist B fragments (static over time): wave w covers cols [w*32, w*32+32)
  bf16x8 bfr[2][16];
  #pragma unroll
  for (int nt = 0; nt < 2; nt++)
    #pragma unroll
    for (int kk = 0; kk < 16; kk++)
      bfr[nt][kk] = *(const bf16x8*)&Ut[(w*32 + nt*16 + i16)*520 + kk*32 + q*8];
  __syncthreads();

  const int erow = tid >> 2;          // batch row 0..63
  const int ecg  = (tid & 3) * 8;     // 8 hidden cells per thread
  float cst[8];
  #pragma unroll
  for (int j = 0; j < 8; j++) cst[j] = 0.f;
  const f32x4 zf4 = {0.f, 0.f, 0.f, 0.f};

  for (int t = 0; t < 512; t++){
    const int tz = dir ? (511 - t) : t;
    // zx gates for this step (normal cached loads; L2 stays warm)
    i32x4 zu[4];
    {
      const u16* zr = zxd + (size_t)(tz*64 + erow) * 2048 + jbase + ecg;
      #pragma unroll
      for (int g = 0; g < 4; g++) zu[g] = *(const i32x4*)(zr + g*512);
    }
    f32x4 acc[4][2];
    #pragma unroll
    for (int mt = 0; mt < 4; mt++){ acc[mt][0] = zf4; acc[mt][1] = zf4; }

    if (t > 0){
      // wait for all 16 producers of h_{t-1}: one coalesced 64B poll line
      if (w == 0 && l < 16){
        const u32* fp = myflags + (size_t)(t-1)*16 + l;
        u32 v;
        do {
          asm volatile("global_load_dword %0, %1, off sc0 sc1\n\ts_waitcnt vmcnt(0)"
                       : "=v"(v) : "v"(fp) : "memory");
        } while (v < (u32)t);
      }
      __syncthreads();
      // read full h_{t-1} (64 KB) straight from the coherence point
      const i32x4* hp = (const i32x4*)(hbuf + ((size_t)(((t-1)&1)*2 + dir)) * 32768) + tid*16;
      i32x4 hv16[16];
      #pragma unroll
      for (int ii = 0; ii < 16; ii++)
        asm volatile("global_load_dwordx4 %0, %1, off sc0 sc1"
                     : "=v"(hv16[ii]) : "v"(hp + ii));
      asm volatile("s_waitcnt vmcnt(0)" ::: "memory");
      i32x4* ldst = (i32x4*)&hA[(tid>>2)*520 + (tid&3)*128];
      #pragma unroll
      for (int ii = 0; ii < 16; ii++) ldst[ii] = hv16[ii];
      __syncthreads();
      #pragma unroll
      for (int kk = 0; kk < 16; kk++){
        bf16x8 a[4];
        #pragma unroll
        for (int mt = 0; mt < 4; mt++)
          a[mt] = *(const bf16x8*)&hA[(mt*16 + i16)*520 + kk*32 + q*8];
        #pragma unroll
        for (int mt = 0; mt < 4; mt++){
          acc[mt][0] = mfma16(a[mt], bfr[0][kk], acc[mt][0]);
          acc[mt][1] = mfma16(a[mt], bfr[1][kk], acc[mt][1]);
        }
      }
    }
    // scatter z to zbuf (C layout row=(lane>>4)*4+reg, col=lane&15)
    #pragma unroll
    for (int mt = 0; mt < 4; mt++)
      #pragma unroll
      for (int nt = 0; nt < 2; nt++)
        #pragma unroll
        for (int rr = 0; rr < 4; rr++)
          zbuf[(mt*16 + q*4 + rr)*132 + w*32 + nt*16 + i16] = acc[mt][nt][rr];
    __syncthreads();
    // elementwise LSTM cell (gate order i,f,g,o)
    float hvf[8];
    i32x4 hpk;
    u16* hpku = (u16*)&hpk;
    #pragma unroll
    for (int j = 0; j < 8; j++){
      const int ch = ecg + j;
      const float* zb = &zbuf[erow*132 + ch];
      float z0 = zb[ 0] + bf2f(((const u16*)&zu[0])[j]);
      float z1 = zb[32] + bf2f(((const u16*)&zu[1])[j]);
      float z2 = zb[64] + bf2f(((const u16*)&zu[2])[j]);
      float z3 = zb[96] + bf2f(((const u16*)&zu[3])[j]);
      float ig = fsig(z0), fg = fsig(z1), gg = ftanh(z2), og = fsig(z3);
      cst[j] = fg * cst[j] + ig * gg;
      hvf[j] = og * ftanh(cst[j]);
      hpku[j] = f2bf(hvf[j]);
    }
    // write h_t slice through to the coherence point; ack before signaling
    u16* hwp = hbuf + ((size_t)((t&1)*2 + dir)) * 32768 + erow*512 + jbase + ecg;
    asm volatile("global_store_dwordx4 %0, %1, off sc0 sc1" :: "v"(hwp), "v"(hpk) : "memory");
    asm volatile("s_waitcnt vmcnt(0)" ::: "memory");
    // out-store issued AFTER the release wait: its ack is off the critical path
    if (OUT_BF16){
      *(i32x4*)(outb + ((size_t)erow*512 + tz)*1024 + dir*512 + jbase + ecg) = hpk;
    } else {
      float* op = outf + ((size_t)erow*512 + tz)*1024 + dir*512 + jbase + ecg;
      float4 f0 = {hvf[0], hvf[1], hvf[2], hvf[3]};
      float4 f1 = {hvf[4], hvf[5], hvf[6], hvf[7]};
      *(float4*)(op) = f0;
      *(float4*)(op + 4) = f1;
    }
    if (t < 511){
      __syncthreads();   // all waves' h-stores acked (each waited its own vmcnt)
      if (tid == 0){
        u32* fp = myflags + (size_t)t*16 + slice;
        u32 val = (u32)(t + 1);
        asm volatile("global_store_dword %0, %1, off sc0 sc1" :: "v"(fp), "v"(val) : "memory");
      }
    }
  }
}

// ---------------------------------------------------------------------------
extern "C" void kernel_launch(void* const* d_in, const int* in_sizes, int n_in,
                              void* d_out, int out_size, void* d_ws, size_t ws_size,
                              hipStream_t stream) {
  const float* x   = (const float*)d_in[0];
  const float* W0f = (const float*)d_in[1];
  const float* U0f = (const float*)d_in[2];
  const float* b0f = (const float*)d_in[3];
  const float* W0b = (const float*)d_in[4];
  const float* U0b = (const float*)d_in[5];
  const float* b0b = (const float*)d_in[6];
  const float* W1f = (const float*)d_in[7];
  const float* U1f = (const float*)d_in[8];
  const float* b1f = (const float*)d_in[9];
  const float* W1b = (const float*)d_in[10];
  const float* U1b = (const float*)d_in[11];
  const float* b1b = (const float*)d_in[12];

  char* ws = (char*)d_ws;
  size_t off = 0;
  u16* Wt0f = (u16*)(ws + off); off += (size_t)2048*512*2;
  u16* Wt0b = (u16*)(ws + off); off += (size_t)2048*512*2;
  u16* Wt1f = (u16*)(ws + off); off += (size_t)2048*1024*2;
  u16* Wt1b = (u16*)(ws + off); off += (size_t)2048*1024*2;
  u16* zx   = (u16*)(ws + off); off += (size_t)2*512*64*2048*2;
  u16* h0   = (u16*)(ws + off); off += (size_t)64*512*1024*2;
  u16* hbuf = (u16*)(ws + off); off += (size_t)2*2*64*512*2;
  u32* flags= (u32*)(ws + off); off += (size_t)2*2*512*16*4;
  (void)ws_size; (void)in_sizes; (void)n_in; (void)out_size;

  hipMemsetAsync(flags, 0, (size_t)2*2*512*16*4, stream);
  hipFuncSetAttribute(reinterpret_cast<const void*>(&lstm_rec<true>),
                      hipFuncAttributeMaxDynamicSharedMemorySize, REC_SMEM);
  hipFuncSetAttribute(reinterpret_cast<const void*>(&lstm_rec<false>),
                      hipFuncAttributeMaxDynamicSharedMemorySize, REC_SMEM);

  transpose_cast<<<dim3(64, 16), 256, 0, stream>>>(W0f, Wt0f, 512);
  transpose_cast<<<dim3(64, 16), 256, 0, stream>>>(W0b, Wt0b, 512);
  transpose_cast<<<dim3(64, 32), 256, 0, stream>>>(W1f, Wt1f, 1024);
  transpose_cast<<<dim3(64, 32), 256, 0, stream>>>(W1b, Wt1b, 1024);

  gemm_zx<float><<<dim3(16, 256, 2), 256, 0, stream>>>(x, Wt0f, Wt0b, b0f, b0b, zx, 512);
  lstm_rec<true><<<32, 256, REC_SMEM, stream>>>(U0f, U0b, zx, hbuf, flags, h0, nullptr);
  gemm_zx<u16><<<dim3(16, 256, 2), 256, 0, stream>>>(h0, Wt1f, Wt1b, b1f, b1b, zx, 1024);
  lstm_rec<false><<<32, 256, REC_SMEM, stream>>>(U1f, U1b, zx, hbuf, flags + 2*512*16,
                                                 nullptr, (float*)d_out);
}